// Round 2
// baseline (4381.820 us; speedup 1.0000x reference)
//
#include <hip/hip_runtime.h>
#include <hip/hip_bf16.h>

// MindSpeedTEGroupedLinear: 64 experts, x[32768,2048]f32 @ W[e][1408,2048]^T f32
#define E_ 64
#define K_ 2048
#define N_ 1408
#define TOKENS_ 32768
#define BM 256
#define BN 128
#define BK 32
#define NK (K_ / BK)                 // 64
#define NTHREADS 512
#define NTILE (N_ / BN)              // 11
#define MT_MAX (TOKENS_ / BM + E_)   // 192 worst-case M-tiles
#define LDSA (BM * BK * 2)           // 16384 B
#define LDSB (BN * BK * 2)           // 8192 B
#define LDSBUF (LDSA + LDSB)         // 24576 B

using f32x4  = __attribute__((ext_vector_type(4))) float;
using bf16x8 = __attribute__((ext_vector_type(8))) short;

// raw barrier: drain LDS ops only; keep global loads in flight across it
#define BAR() asm volatile("s_waitcnt lgkmcnt(0)\n\ts_barrier" ::: "memory")

__device__ __forceinline__ short f2b(float f) {
  __hip_bfloat16 h = __float2bfloat16(f);
  return __builtin_bit_cast(short, h);
}

__global__ void build_tiles(const int* __restrict__ m_splits, int4* __restrict__ table,
                            int* __restrict__ count) {
  if (threadIdx.x == 0 && blockIdx.x == 0) {
    int off = 0, t = 0;
    for (int e = 0; e < E_; ++e) {
      int m = m_splits[e];
      for (int r = 0; r < m; r += BM) {
        table[t] = make_int4(e, off + r, min(BM, m - r), 0);
        ++t;
      }
      off += m;
    }
    *count = t;
  }
}

struct Stage { f32x4 a[2][2]; f32x4 b[2]; };

__global__ __launch_bounds__(NTHREADS, 6) void gemm_grouped(
    const float* __restrict__ x, const float* __restrict__ W,
    const int4* __restrict__ table, const int* __restrict__ count,
    float* __restrict__ out) {
  __shared__ char smem[2 * LDSBUF];   // 48 KiB -> 3 blocks/CU

  // XCD-aware mapping: the 11 N-blocks of one M-tile land on one XCD,
  // consecutive M-tiles of one expert stay on that XCD (L2 x-reuse, L3 W-reuse).
  const int nmt = *count;
  const int gpx = (nmt + 7) >> 3;
  const int p = blockIdx.x;
  if (p >= 8 * gpx * NTILE) return;
  const int xcd = p & 7;
  const int s = p >> 3;
  const int g = s / NTILE;
  const int nt = s - g * NTILE;
  const int mt = xcd * gpx + g;
  if (mt >= nmt) return;

  const int4 te = table[mt];
  const int expert = te.x, row0 = te.y, nrows = te.z;
  const int n0 = nt * BN;

  const int tid  = threadIdx.x;
  const int lane = tid & 63;
  const int w    = tid >> 6;   // 8 waves
  const int wm   = w >> 1;     // 0..3 (64-row stripe)
  const int wn   = w & 1;      // 0..1 (64-col stripe)

  const int strow = tid >> 2;        // staging row 0..127
  const int skc8  = (tid & 3) * 8;   // k-offset (floats) of this thread's 8-elem chunk
  const int kcb   = (tid & 3) * 16;  // byte offset of chunk within 64 B LDS row

  const float* xrow = x + (size_t)row0 * K_;
  const float* wrow = W + ((size_t)expert * N_ + (size_t)n0) * K_;

  const f32x4 zero4 = {0.f, 0.f, 0.f, 0.f};

  auto load_tiles = [&](int kt, Stage& st) {
    const int kbase = kt * BK + skc8;
#pragma unroll
    for (int c = 0; c < 2; ++c) {
      const int r = c * 128 + strow;
      if (r < nrows) {
        const float* pp = xrow + (size_t)r * K_ + kbase;
        st.a[c][0] = *(const f32x4*)pp;
        st.a[c][1] = *(const f32x4*)(pp + 4);
      } else { st.a[c][0] = zero4; st.a[c][1] = zero4; }
    }
    const float* q = wrow + (size_t)strow * K_ + kbase;
    st.b[0] = *(const f32x4*)q;
    st.b[1] = *(const f32x4*)(q + 4);
  };

  // 64 B rows, 4x16B slots; swizzle slot ^= (r>>1)&3 -> frag reads 2-way (free)
  auto write_lds = [&](int buf, const Stage& st) {
    const int base = buf * LDSBUF;
#pragma unroll
    for (int c = 0; c < 2; ++c) {
      const int r = c * 128 + strow;
      const int off = r * 64 + (kcb ^ (((r >> 1) & 3) << 4));
      bf16x8 v;
#pragma unroll
      for (int i = 0; i < 4; ++i) { v[i] = f2b(st.a[c][0][i]); v[i + 4] = f2b(st.a[c][1][i]); }
      *(bf16x8*)(smem + base + off) = v;
    }
    {
      const int r = strow;
      const int off = r * 64 + (kcb ^ (((r >> 1) & 3) << 4));
      bf16x8 v;
#pragma unroll
      for (int i = 0; i < 4; ++i) { v[i] = f2b(st.b[0][i]); v[i + 4] = f2b(st.b[1][i]); }
      *(bf16x8*)(smem + base + LDSA + off) = v;
    }
  };

  f32x4 acc[4][4];
#pragma unroll
  for (int i = 0; i < 4; ++i)
#pragma unroll
    for (int j = 0; j < 4; ++j) acc[i][j] = zero4;

  const int arow0 = wm * 64 + (lane & 15);
  const int brow0 = wn * 64 + (lane & 15);
  const int kslot = (lane >> 4) * 16;   // byte offset of lane's 8-elem k-group

  auto compute = [&](int buf) {
    const int base = buf * LDSBUF;
    bf16x8 af[4], bfr[4];
#pragma unroll
    for (int i = 0; i < 4; ++i) {
      const int r = arow0 + i * 16;
      af[i] = *(const bf16x8*)(smem + base + r * 64 + (kslot ^ (((r >> 1) & 3) << 4)));
    }
#pragma unroll
    for (int j = 0; j < 4; ++j) {
      const int r = brow0 + j * 16;
      bfr[j] = *(const bf16x8*)(smem + base + LDSA + r * 64 + (kslot ^ (((r >> 1) & 3) << 4)));
    }
#pragma unroll
    for (int i = 0; i < 4; ++i)
#pragma unroll
      for (int j = 0; j < 4; ++j)
        acc[i][j] = __builtin_amdgcn_mfma_f32_16x16x32_bf16(af[i], bfr[j], acc[i][j], 0, 0, 0);
  };

  // 2-deep register prefetch, double-buffered LDS, 1 barrier per K-tile.
  Stage sA, sB;
  load_tiles(0, sA);
  load_tiles(1, sB);
  write_lds(0, sA);
  for (int kt = 0; kt < NK; kt += 2) {
    if (kt + 2 < NK) load_tiles(kt + 2, sA);
    BAR();                      // publishes buf0 (tile kt); all waves done reading buf0's prev use
    compute(0);
    write_lds(1, sB);           // tile kt+1 (waits counted vmcnt on sB only)
    if (kt + 3 < NK) load_tiles(kt + 3, sB);
    BAR();                      // publishes buf1 (tile kt+1)
    compute(1);
    if (kt + 2 < NK) write_lds(0, sA);  // tile kt+2
  }

  // epilogue: C/D layout col=lane&15, row=(lane>>4)*4+reg
  const int crow = wm * 64 + (lane >> 4) * 4;
  const int ccol = n0 + wn * 64 + (lane & 15);
#pragma unroll
  for (int i = 0; i < 4; ++i) {
#pragma unroll
    for (int rr = 0; rr < 4; ++rr) {
      const int lr = crow + i * 16 + rr;
      if (lr < nrows) {
#pragma unroll
        for (int j = 0; j < 4; ++j)
          out[(size_t)(row0 + lr) * N_ + ccol + j * 16] = acc[i][j][rr];
      }
    }
  }
}

extern "C" void kernel_launch(void* const* d_in, const int* in_sizes, int n_in,
                              void* d_out, int out_size, void* d_ws, size_t ws_size,
                              hipStream_t stream) {
  const float* x        = (const float*)d_in[0];
  const float* W        = (const float*)d_in[1];
  const int*   m_splits = (const int*)d_in[2];
  float*       out      = (float*)d_out;

  int*  count = (int*)d_ws;
  int4* table = (int4*)((char*)d_ws + 16);

  build_tiles<<<1, 64, 0, stream>>>(m_splits, table, count);

  const int nblocks = 8 * ((MT_MAX + 7) / 8) * NTILE;  // 2112; excess early-exit
  gemm_grouped<<<nblocks, NTHREADS, 0, stream>>>(x, W, table, count, out);
}

// Round 3
// 687.076 us; speedup vs baseline: 6.3775x; 6.3775x over previous
//
#include <hip/hip_runtime.h>
#include <hip/hip_bf16.h>

// MindSpeedTEGroupedLinear: 64 experts, x[32768,2048]f32 @ W[e][1408,2048]^T f32
#define E_ 64
#define K_ 2048
#define N_ 1408
#define BM 256
#define BN 128
#define BK 32
#define NK (K_ / BK)              // 64
#define NTHREADS 512
#define NTILE (N_ / BN)           // 11
#define LDSA (BM * BK * 2)        // 16384 B
#define LDSB (BN * BK * 2)        // 8192 B
#define LDSBUF (LDSA + LDSB)      // 24576 B

using f32x4  = __attribute__((ext_vector_type(4))) float;
using bf16x8 = __attribute__((ext_vector_type(8))) short;

// Drain LDS ops only; global loads stay in flight across the barrier.
#define BAR() asm volatile("s_waitcnt lgkmcnt(0)\n\ts_barrier" ::: "memory")

__device__ __forceinline__ short f2b(float f) {
  __hip_bfloat16 h = __float2bfloat16(f);
  return __builtin_bit_cast(short, h);
}

// offs[e] = row offset of expert e; order[] = experts sorted by descending m (LPT).
__global__ void build_meta(const int* __restrict__ m_splits, int* __restrict__ offs,
                           int* __restrict__ order) {
  if (threadIdx.x == 0 && blockIdx.x == 0) {
    int off = 0;
    for (int e = 0; e < E_; ++e) { offs[e] = off; off += m_splits[e]; }
    for (int e = 0; e < E_; ++e) order[e] = e;
    for (int i = 1; i < E_; ++i) {          // insertion sort, descending m
      int v = order[i], mv = m_splits[v], j = i - 1;
      while (j >= 0 && m_splits[order[j]] < mv) { order[j + 1] = order[j]; --j; }
      order[j + 1] = v;
    }
  }
}

struct Stage { f32x4 a[2][2]; f32x4 b[2]; };

__global__ __launch_bounds__(NTHREADS, 2) void gemm_grouped(
    const float* __restrict__ x, const float* __restrict__ W,
    const int* __restrict__ m_splits, const int* __restrict__ offs,
    const int* __restrict__ order, float* __restrict__ out) {
  __shared__ char smem[2 * LDSBUF];   // 48 KiB

  // one block per (expert, N-tile); M-tiles looped inside -> W slice read from
  // HBM once per block, later M-tiles hit this XCD's L2.
  const int e  = order[blockIdx.x / NTILE];
  const int nt = blockIdx.x % NTILE;
  const int row_base = offs[e];
  const int m_e = m_splits[e];
  const int n0 = nt * BN;

  const int tid  = threadIdx.x;
  const int lane = tid & 63;
  const int w    = tid >> 6;   // 8 waves
  const int wm   = w >> 1;     // 0..3 (64-row stripe of 256)
  const int wn   = w & 1;      // 0..1 (64-col stripe of 128)

  const int strow = tid >> 2;        // staging row 0..127
  const int skc8  = (tid & 3) * 8;   // k-offset (floats) of this thread's chunk
  const int kcb   = (tid & 3) * 16;  // byte offset within 64 B LDS row

  const float* wrow = W + ((size_t)e * N_ + (size_t)n0) * K_;
  const f32x4 zero4 = {0.f, 0.f, 0.f, 0.f};

  const int arow0 = wm * 64 + (lane & 15);
  const int brow0 = wn * 64 + (lane & 15);
  const int kslot = (lane >> 4) * 16;

  for (int r0 = 0; r0 < m_e; r0 += BM) {
    const int nrows = min(BM, m_e - r0);
    const float* xrow = x + (size_t)(row_base + r0) * K_;

    auto load_tiles = [&](int kt, Stage& st) {
      const int kbase = kt * BK + skc8;
#pragma unroll
      for (int c = 0; c < 2; ++c) {
        const int r = c * 128 + strow;
        if (r < nrows) {
          const float* pp = xrow + (size_t)r * K_ + kbase;
          st.a[c][0] = *(const f32x4*)pp;
          st.a[c][1] = *(const f32x4*)(pp + 4);
        } else { st.a[c][0] = zero4; st.a[c][1] = zero4; }
      }
      const float* q = wrow + (size_t)strow * K_ + kbase;
      st.b[0] = *(const f32x4*)q;
      st.b[1] = *(const f32x4*)(q + 4);
    };

    // 64 B rows, 4x16B slots; slot ^= (r>>1)&3 -> frag reads conflict-free
    auto write_lds = [&](int buf, const Stage& st) {
      const int base = buf * LDSBUF;
#pragma unroll
      for (int c = 0; c < 2; ++c) {
        const int r = c * 128 + strow;
        const int off = r * 64 + (kcb ^ (((r >> 1) & 3) << 4));
        bf16x8 v;
#pragma unroll
        for (int i = 0; i < 4; ++i) { v[i] = f2b(st.a[c][0][i]); v[i + 4] = f2b(st.a[c][1][i]); }
        *(bf16x8*)(smem + base + off) = v;
      }
      {
        const int r = strow;
        const int off = r * 64 + (kcb ^ (((r >> 1) & 3) << 4));
        bf16x8 v;
#pragma unroll
        for (int i = 0; i < 4; ++i) { v[i] = f2b(st.b[0][i]); v[i + 4] = f2b(st.b[1][i]); }
        *(bf16x8*)(smem + base + LDSA + off) = v;
      }
    };

    f32x4 acc[4][4];
#pragma unroll
    for (int i = 0; i < 4; ++i)
#pragma unroll
      for (int j = 0; j < 4; ++j) acc[i][j] = zero4;

    auto compute = [&](int buf) {
      const int base = buf * LDSBUF;
      bf16x8 af[4], bfr[4];
#pragma unroll
      for (int i = 0; i < 4; ++i) {
        const int r = arow0 + i * 16;
        af[i] = *(const bf16x8*)(smem + base + r * 64 + (kslot ^ (((r >> 1) & 3) << 4)));
      }
#pragma unroll
      for (int j = 0; j < 4; ++j) {
        const int r = brow0 + j * 16;
        bfr[j] = *(const bf16x8*)(smem + base + LDSA + r * 64 + (kslot ^ (((r >> 1) & 3) << 4)));
      }
#pragma unroll
      for (int i = 0; i < 4; ++i)
#pragma unroll
        for (int j = 0; j < 4; ++j)
          acc[i][j] = __builtin_amdgcn_mfma_f32_16x16x32_bf16(af[i], bfr[j], acc[i][j], 0, 0, 0);
    };

    // 1-deep prefetch, double-buffered LDS, one lgkm-barrier per K-tile;
    // global loads stay in flight across the barrier (vmcnt waited only at
    // write_lds register use, after compute has run).
    Stage sA;
    load_tiles(0, sA);
    BAR();                 // all waves done reading smem (prev M-tile)
    write_lds(0, sA);
    int cur = 0;
    for (int kt = 0; kt < NK; ++kt) {
      if (kt + 1 < NK) load_tiles(kt + 1, sA);
      BAR();                                // publishes buf `cur`
      compute(cur);
      if (kt + 1 < NK) write_lds(cur ^ 1, sA);
      cur ^= 1;
    }

    // epilogue: C/D layout col=lane&15, row=(lane>>4)*4+reg
    const int crow = wm * 64 + (lane >> 4) * 4;
    const int ccol = n0 + wn * 64 + (lane & 15);
#pragma unroll
    for (int i = 0; i < 4; ++i) {
#pragma unroll
      for (int rr = 0; rr < 4; ++rr) {
        const int lr = crow + i * 16 + rr;
        if (lr < nrows) {
#pragma unroll
          for (int j = 0; j < 4; ++j)
            out[(size_t)(row_base + r0 + lr) * N_ + ccol + j * 16] = acc[i][j][rr];
        }
      }
    }
  }
}

extern "C" void kernel_launch(void* const* d_in, const int* in_sizes, int n_in,
                              void* d_out, int out_size, void* d_ws, size_t ws_size,
                              hipStream_t stream) {
  const float* x        = (const float*)d_in[0];
  const float* W        = (const float*)d_in[1];
  const int*   m_splits = (const int*)d_in[2];
  float*       out      = (float*)d_out;

  int* offs  = (int*)d_ws;              // E_ ints
  int* order = (int*)d_ws + E_;         // E_ ints

  build_meta<<<1, 64, 0, stream>>>(m_splits, offs, order);
  gemm_grouped<<<E_ * NTILE, NTHREADS, 0, stream>>>(x, W, m_splits, offs, order, out);
}